// Round 2
// baseline (1341.295 us; speedup 1.0000x reference)
//
#include <hip/hip_runtime.h>

#define NND 50000
#define NE  800000
#define IND 128
#define HD  256
#define OD  256
#define NH  8
#define ED  64
#define KVIN 320   // 64 + 128 + 128

typedef __attribute__((ext_vector_type(8))) short bf16x8;
typedef __attribute__((ext_vector_type(4))) float f32x4;

__device__ __forceinline__ float bf2f(unsigned short u) {
    union { unsigned int i; float f; } x; x.i = ((unsigned int)u) << 16; return x.f;
}
__device__ __forceinline__ unsigned short f2bf(float f) {
    union { float f; unsigned int i; } x; x.f = f;
    unsigned int u = x.i;
    u += 0x7FFFu + ((u >> 16) & 1u);   // RNE
    return (unsigned short)(u >> 16);
}

// ---------------- counting sort by dst ----------------
__global__ void k_hist(const int* __restrict__ eidx, int* __restrict__ cnt) {
    int e = blockIdx.x * 256 + threadIdx.x;
    if (e < NE) atomicAdd(&cnt[eidx[NE + e]], 1);
}

__global__ __launch_bounds__(1024) void k_scan(const int* __restrict__ cnt,
                                               int* __restrict__ head) {
    __shared__ int part[1024];
    const int t = threadIdx.x;
    const int CH = (NND + 1023) / 1024;   // 49
    int base = t * CH;
    int s = 0;
    for (int i = 0; i < CH; ++i) { int idx = base + i; if (idx < NND) s += cnt[idx]; }
    part[t] = s;
    __syncthreads();
    for (int off = 1; off < 1024; off <<= 1) {
        int v = (t >= off) ? part[t - off] : 0;
        __syncthreads();
        part[t] += v;
        __syncthreads();
    }
    int excl = (t == 0) ? 0 : part[t - 1];
    for (int i = 0; i < CH; ++i) {
        int idx = base + i; if (idx >= NND) break;
        head[idx] = excl;
        excl += cnt[idx];
    }
}

__global__ void k_scatter(const int* __restrict__ eidx, int* __restrict__ head,
                          int* __restrict__ perm) {
    int e = blockIdx.x * 256 + threadIdx.x;
    if (e < NE) {
        int d = eidx[NE + e];
        int pos = atomicAdd(&head[d], 1);
        perm[pos] = e;
    }
}

// ---------------- weight pack ----------------
// P[((ct*KS+ks)*64 + l)*8 + j] = bf16( W[k*N + n] ),  n = ct*16 + (l&15),
// k = ks*32 + (l>>4)*8 + j.  B-fragment for mfma_f32_16x16x32_bf16.
__global__ void k_packw(const float* __restrict__ W, unsigned short* __restrict__ P,
                        int K, int N) {
    int tid = blockIdx.x * 256 + threadIdx.x;
    if (tid >= K * N) return;
    int j = tid & 7;
    int l = (tid >> 3) & 63;
    int rest = tid >> 9;
    int KS = K >> 5;
    int ks = rest % KS;
    int ct = rest / KS;
    int n = ct * 16 + (l & 15);
    int k = ks * 32 + (l >> 4) * 8 + j;
    P[tid] = f2bf(W[k * N + n]);
}

__global__ void k_h2bf(const float* __restrict__ h, unsigned short* __restrict__ hb, int n4) {
    int i = blockIdx.x * 256 + threadIdx.x;
    if (i < n4) {
        float4 v = *(const float4*)(h + (size_t)i * 4);
        ushort4 o;
        o.x = f2bf(v.x); o.y = f2bf(v.y); o.z = f2bf(v.z); o.w = f2bf(v.w);
        *(ushort4*)(hb + (size_t)i * 4) = o;
    }
}

// ---------------- MFMA helpers ----------------
__device__ __forceinline__ void zero_acc(f32x4 (&acc)[4][4]) {
    #pragma unroll
    for (int i = 0; i < 4; ++i)
        #pragma unroll
        for (int c = 0; c < 4; ++c)
            #pragma unroll
            for (int r = 0; r < 4; ++r) acc[i][c][r] = 0.f;
}

template<int KS, int STRIDE>
__device__ __forceinline__ void gemm_step(const unsigned short* A,
                                          const unsigned short* __restrict__ Wp,
                                          int w, int l, f32x4 (&acc)[4][4]) {
    for (int ks = 0; ks < KS; ++ks) {
        bf16x8 a[4], b[4];
        #pragma unroll
        for (int i = 0; i < 4; ++i)
            a[i] = *(const bf16x8*)(A + (i * 16 + (l & 15)) * STRIDE + ks * 32 + (l >> 4) * 8);
        #pragma unroll
        for (int c = 0; c < 4; ++c)
            b[c] = *(const bf16x8*)(Wp + (((4 * w + c) * KS + ks) * 64 + l) * 8);
        #pragma unroll
        for (int i = 0; i < 4; ++i)
            #pragma unroll
            for (int c = 0; c < 4; ++c)
                acc[i][c] = __builtin_amdgcn_mfma_f32_16x16x32_bf16(a[i], b[c], acc[i][c], 0, 0, 0);
    }
}

// ---------------- Q = MLP(h) ----------------
__global__ __launch_bounds__(256) void k_qmlp(
    const unsigned short* __restrict__ hb,
    const unsigned short* __restrict__ W1p, const float* __restrict__ b1,
    const unsigned short* __restrict__ W2p, const float* __restrict__ b2,
    unsigned short* __restrict__ qb)
{
    __shared__ unsigned short sX[64][136];
    __shared__ unsigned short sH[64][264];
    const int t = threadIdx.x, w = t >> 6, l = t & 63;
    const int m0 = blockIdx.x * 64;

    for (int c = t; c < 1024; c += 256) {
        int row = c >> 4, j = c & 15;
        int srcr = m0 + row; if (srcr >= NND) srcr = NND - 1;
        *(bf16x8*)(&sX[row][j * 8]) = *(const bf16x8*)(hb + (size_t)srcr * IND + j * 8);
    }
    __syncthreads();

    f32x4 acc[4][4];
    zero_acc(acc);
    gemm_step<4, 136>(&sX[0][0], W1p, w, l, acc);

    float bias1[4];
    #pragma unroll
    for (int c = 0; c < 4; ++c) bias1[c] = b1[64 * w + 16 * c + (l & 15)];
    #pragma unroll
    for (int i = 0; i < 4; ++i)
        #pragma unroll
        for (int c = 0; c < 4; ++c)
            #pragma unroll
            for (int r = 0; r < 4; ++r) {
                float v = acc[i][c][r] + bias1[c];
                v = v > 0.f ? v : 0.f;
                sH[i * 16 + (l >> 4) * 4 + r][64 * w + 16 * c + (l & 15)] = f2bf(v);
            }
    __syncthreads();

    zero_acc(acc);
    gemm_step<8, 264>(&sH[0][0], W2p, w, l, acc);

    float bias2[4];
    #pragma unroll
    for (int c = 0; c < 4; ++c) bias2[c] = b2[64 * w + 16 * c + (l & 15)];
    #pragma unroll
    for (int i = 0; i < 4; ++i)
        #pragma unroll
        for (int c = 0; c < 4; ++c)
            #pragma unroll
            for (int r = 0; r < 4; ++r) {
                int row = m0 + i * 16 + (l >> 4) * 4 + r;
                if (row < NND)
                    qb[(size_t)row * OD + 64 * w + 16 * c + (l & 15)] =
                        f2bf(acc[i][c][r] + bias2[c]);
            }
}

// ---------------- per-edge MLP passes (dst-sorted order) ----------------
// MODE 0: k = MLP_k(kv); ex = exp(q[dst].k/sqrt(32)); exbuf[pos]=ex; den += seg-sum(ex)
// MODE 1: v = MLP_v(kv); out[dst] += seg-sum( (ex/den[dst]) * v )
struct SMemEdge {
    union {
        struct {
            unsigned short X[64][328];   // 41,984 B (input tile)
            unsigned short H[64][264];   // 33,792 B (hidden / k output)
        };
        float V[64][260];                // 66,560 B (weighted v, post-GEMM2, MODE1)
    };
    int   Eid[64];
    int   Src[64];
    int   Dst[64];
    float Ex[64][8];                     // ex (MODE0) / alpha (MODE1)
};

template<int MODE>
__global__ __launch_bounds__(256) void k_edge(
    const float* __restrict__ eattr,
    const unsigned short* __restrict__ hb,
    const int* __restrict__ eidx,
    const int* __restrict__ perm,
    const unsigned short* __restrict__ W1p, const float* __restrict__ b1,
    const unsigned short* __restrict__ W2p, const float* __restrict__ b2,
    const unsigned short* __restrict__ qb,
    float* __restrict__ exbuf,
    float* __restrict__ den,
    float* __restrict__ outp)
{
    __shared__ SMemEdge sm;
    const int t = threadIdx.x, w = t >> 6, l = t & 63;
    const int e0 = blockIdx.x * 64;

    if (t < 64) {
        int eid = perm[e0 + t];
        sm.Eid[t] = eid;
        sm.Src[t] = eidx[eid];
        sm.Dst[t] = eidx[NE + eid];
    }
    __syncthreads();

    // stage edge attrs (cols 0..63), fp32 -> bf16
    for (int c = t; c < 1024; c += 256) {
        int row = c >> 4, j = c & 15;
        float4 v = *(const float4*)(eattr + (size_t)sm.Eid[row] * ED + j * 4);
        ushort4 o; o.x = f2bf(v.x); o.y = f2bf(v.y); o.z = f2bf(v.z); o.w = f2bf(v.w);
        *(ushort4*)(&sm.X[row][j * 4]) = o;
    }
    // gather h[dst] (cols 64..191) and h[src] (cols 192..319)
    for (int c = t; c < 1024; c += 256) {
        int row = c >> 4, j = c & 15;
        *(bf16x8*)(&sm.X[row][64 + j * 8]) = *(const bf16x8*)(hb + (size_t)sm.Dst[row] * IND + j * 8);
    }
    for (int c = t; c < 1024; c += 256) {
        int row = c >> 4, j = c & 15;
        *(bf16x8*)(&sm.X[row][192 + j * 8]) = *(const bf16x8*)(hb + (size_t)sm.Src[row] * IND + j * 8);
    }
    if (MODE == 1) {
        for (int p = t; p < 512; p += 256) {
            int er = p >> 3, hh = p & 7;
            sm.Ex[er][hh] = exbuf[(size_t)(e0 + er) * NH + hh] / den[sm.Dst[er] * NH + hh];
        }
    }
    __syncthreads();

    f32x4 acc[4][4];
    zero_acc(acc);
    gemm_step<10, 328>(&sm.X[0][0], W1p, w, l, acc);

    float bias1[4];
    #pragma unroll
    for (int c = 0; c < 4; ++c) bias1[c] = b1[64 * w + 16 * c + (l & 15)];
    #pragma unroll
    for (int i = 0; i < 4; ++i)
        #pragma unroll
        for (int c = 0; c < 4; ++c)
            #pragma unroll
            for (int r = 0; r < 4; ++r) {
                float v = acc[i][c][r] + bias1[c];
                v = v > 0.f ? v : 0.f;
                sm.H[i * 16 + (l >> 4) * 4 + r][64 * w + 16 * c + (l & 15)] = f2bf(v);
            }
    __syncthreads();

    zero_acc(acc);
    gemm_step<8, 264>(&sm.H[0][0], W2p, w, l, acc);

    float bias2[4];
    #pragma unroll
    for (int c = 0; c < 4; ++c) bias2[c] = b2[64 * w + 16 * c + (l & 15)];

    if (MODE == 0) {
        __syncthreads();   // all waves done reading sm.H
        #pragma unroll
        for (int i = 0; i < 4; ++i)
            #pragma unroll
            for (int c = 0; c < 4; ++c)
                #pragma unroll
                for (int r = 0; r < 4; ++r)
                    sm.H[i * 16 + (l >> 4) * 4 + r][64 * w + 16 * c + (l & 15)] =
                        f2bf(acc[i][c][r] + bias2[c]);
        __syncthreads();
        const float scale = 0.17677669529663687f;   // 1/sqrt(32)
        for (int p = t; p < 512; p += 256) {
            int er = p >> 3, hh = p & 7;
            int dn = sm.Dst[er];
            const unsigned short* qrow = qb + (size_t)dn * OD + hh * 32;
            float s = 0.f;
            #pragma unroll
            for (int jj = 0; jj < 32; jj += 8) {
                bf16x8 qv = *(const bf16x8*)(qrow + jj);
                bf16x8 kv = *(const bf16x8*)(&sm.H[er][hh * 32 + jj]);
                #pragma unroll
                for (int u = 0; u < 8; ++u)
                    s += bf2f((unsigned short)qv[u]) * bf2f((unsigned short)kv[u]);
            }
            float ex = __expf(s * scale);
            exbuf[(size_t)(e0 + er) * NH + hh] = ex;
            sm.Ex[er][hh] = ex;
        }
        __syncthreads();
        if (t < NH) {   // per-head segment-sum of ex into den (few atomics)
            float run = 0.f; int prev = sm.Dst[0];
            for (int er = 0; er < 64; ++er) {
                int dn = sm.Dst[er];
                if (dn != prev) { atomicAdd(&den[prev * NH + t], run); run = 0.f; prev = dn; }
                run += sm.Ex[er][t];
            }
            atomicAdd(&den[prev * NH + t], run);
        }
    } else {
        // stash alpha + dst (sm.V overlays sm.X/sm.H) then write weighted v
        float myAlpha[4][4];
        #pragma unroll
        for (int i = 0; i < 4; ++i)
            #pragma unroll
            for (int c = 0; c < 4; ++c) {
                int hh = (64 * w + 16 * c + (l & 15)) >> 5;
                // rows for r=0..3 share er base; alpha depends on (er,hh)
                myAlpha[i][c] = 0.f;  // placeholder; real read below per r
            }
        __syncthreads();   // all waves done reading sm.H (GEMM2 inputs dead)
        #pragma unroll
        for (int i = 0; i < 4; ++i)
            #pragma unroll
            for (int c = 0; c < 4; ++c) {
                int col = 64 * w + 16 * c + (l & 15);
                int hh = col >> 5;
                #pragma unroll
                for (int r = 0; r < 4; ++r) {
                    int er = i * 16 + (l >> 4) * 4 + r;
                    sm.V[er][col] = (acc[i][c][r] + bias2[c]) * sm.Ex[er][hh];
                }
            }
        __syncthreads();
        // column-parallel segment reduction over sorted rows; thread t owns col t
        {
            float run = 0.f; int prev = sm.Dst[0];
            for (int er = 0; er < 64; ++er) {
                int dn = sm.Dst[er];
                if (dn != prev) {
                    atomicAdd(outp + (size_t)prev * OD + t, run);
                    run = 0.f; prev = dn;
                }
                run += sm.V[er][t];
            }
            atomicAdd(outp + (size_t)prev * OD + t, run);
        }
        (void)myAlpha;
    }
}

// ---------------- launcher ----------------
extern "C" void kernel_launch(void* const* d_in, const int* in_sizes, int n_in,
                              void* d_out, int out_size, void* d_ws, size_t ws_size,
                              hipStream_t stream)
{
    const float* h   = (const float*)d_in[0];
    const float* e   = (const float*)d_in[1];
    const int*   eid = (const int*)  d_in[2];
    const float* Wk1 = (const float*)d_in[3];
    const float* bk1 = (const float*)d_in[4];
    const float* Wk2 = (const float*)d_in[5];
    const float* bk2 = (const float*)d_in[6];
    const float* Wv1 = (const float*)d_in[7];
    const float* bv1 = (const float*)d_in[8];
    const float* Wv2 = (const float*)d_in[9];
    const float* bv2 = (const float*)d_in[10];
    const float* Wq1 = (const float*)d_in[11];
    const float* bq1 = (const float*)d_in[12];
    const float* Wq2 = (const float*)d_in[13];
    const float* bq2 = (const float*)d_in[14];

    // workspace layout (bytes)
    char* ws = (char*)d_ws;
    unsigned short* hb   = (unsigned short*)(ws + 0);            // 12,800,000
    unsigned short* Wq1p = (unsigned short*)(ws + 12800000);     //     65,536
    unsigned short* Wq2p = (unsigned short*)(ws + 12865536);     //    131,072
    unsigned short* Wk1p = (unsigned short*)(ws + 12996608);     //    163,840
    unsigned short* Wk2p = (unsigned short*)(ws + 13160448);     //    131,072
    unsigned short* Wv1p = (unsigned short*)(ws + 13291520);     //    163,840
    unsigned short* Wv2p = (unsigned short*)(ws + 13455360);     //    131,072
    unsigned short* qb   = (unsigned short*)(ws + 13586432);     // 25,600,000
    float*          exb  = (float*)         (ws + 39186432);     // 25,600,000
    float*          den  = (float*)         (ws + 64786432);     //  1,600,000
    int*            cnt  = (int*)           (ws + 66386432);     //    200,000
    int*            head = (int*)           (ws + 66586432);     //    200,000
    int*            perm = (int*)           (ws + 66786432);     //  3,200,000
    const size_t needed = 69986432;
    if (ws_size < needed) return;   // insufficient scratch -> fail validation visibly

    hipMemsetAsync(d_out, 0, (size_t)NND * OD * sizeof(float), stream);
    hipMemsetAsync(den, 0, (size_t)NND * NH * sizeof(float), stream);
    hipMemsetAsync(cnt, 0, (size_t)NND * sizeof(int), stream);

    // counting sort of edges by dst
    k_hist<<<(NE + 255) / 256, 256, 0, stream>>>(eid, cnt);
    k_scan<<<1, 1024, 0, stream>>>(cnt, head);
    k_scatter<<<(NE + 255) / 256, 256, 0, stream>>>(eid, head, perm);

    k_h2bf<<<(NND * IND / 4 + 255) / 256, 256, 0, stream>>>(h, hb, NND * IND / 4);
    k_packw<<<(IND * HD + 255) / 256, 256, 0, stream>>>(Wq1, Wq1p, IND, HD);
    k_packw<<<(HD * OD + 255) / 256, 256, 0, stream>>>(Wq2, Wq2p, HD, OD);
    k_packw<<<(KVIN * HD + 255) / 256, 256, 0, stream>>>(Wk1, Wk1p, KVIN, HD);
    k_packw<<<(HD * OD + 255) / 256, 256, 0, stream>>>(Wk2, Wk2p, HD, OD);
    k_packw<<<(KVIN * HD + 255) / 256, 256, 0, stream>>>(Wv1, Wv1p, KVIN, HD);
    k_packw<<<(HD * OD + 255) / 256, 256, 0, stream>>>(Wv2, Wv2p, HD, OD);

    k_qmlp<<<(NND + 63) / 64, 256, 0, stream>>>(hb, Wq1p, bq1, Wq2p, bq2, qb);

    k_edge<0><<<NE / 64, 256, 0, stream>>>(e, hb, eid, perm, Wk1p, bk1, Wk2p, bk2,
                                           qb, exb, den, nullptr);
    k_edge<1><<<NE / 64, 256, 0, stream>>>(e, hb, eid, perm, Wv1p, bv1, Wv2p, bv2,
                                           nullptr, exb, den, (float*)d_out);
}

// Round 3
// 921.733 us; speedup vs baseline: 1.4552x; 1.4552x over previous
//
#include <hip/hip_runtime.h>

#define NND 50000
#define NE  800000
#define IND 128
#define HD  256
#define OD  256
#define NH  8
#define ED  64
#define KVIN 320   // 64 + 128 + 128

typedef __attribute__((ext_vector_type(8))) short bf16x8;
typedef __attribute__((ext_vector_type(4))) float f32x4;

__device__ __forceinline__ float bf2f(unsigned short u) {
    union { unsigned int i; float f; } x; x.i = ((unsigned int)u) << 16; return x.f;
}
__device__ __forceinline__ unsigned short f2bf(float f) {
    union { float f; unsigned int i; } x; x.f = f;
    unsigned int u = x.i;
    u += 0x7FFFu + ((u >> 16) & 1u);   // RNE
    return (unsigned short)(u >> 16);
}

// ---------------- counting sort by dst ----------------
__global__ void k_hist(const int* __restrict__ eidx, int* __restrict__ cnt) {
    int e = blockIdx.x * 256 + threadIdx.x;
    if (e < NE) atomicAdd(&cnt[eidx[NE + e]], 1);
}

__global__ __launch_bounds__(1024) void k_scan(const int* __restrict__ cnt,
                                               int* __restrict__ head) {
    __shared__ int part[1024];
    const int t = threadIdx.x;
    const int CH = (NND + 1023) / 1024;   // 49
    int base = t * CH;
    int s = 0;
    for (int i = 0; i < CH; ++i) { int idx = base + i; if (idx < NND) s += cnt[idx]; }
    part[t] = s;
    __syncthreads();
    for (int off = 1; off < 1024; off <<= 1) {
        int v = (t >= off) ? part[t - off] : 0;
        __syncthreads();
        part[t] += v;
        __syncthreads();
    }
    int excl = (t == 0) ? 0 : part[t - 1];
    for (int i = 0; i < CH; ++i) {
        int idx = base + i; if (idx >= NND) break;
        head[idx] = excl;
        excl += cnt[idx];
    }
}

__global__ void k_scatter(const int* __restrict__ eidx, int* __restrict__ head,
                          int* __restrict__ perm) {
    int e = blockIdx.x * 256 + threadIdx.x;
    if (e < NE) {
        int d = eidx[NE + e];
        int pos = atomicAdd(&head[d], 1);
        perm[pos] = e;
    }
}

// ---------------- weight pack ----------------
// B-fragment pack for mfma_f32_16x16x32_bf16 from a row slice of W:
// P[((ct*KS+ks)*64 + l)*8 + j] = bf16( W[(rowoff + k)*N + n] ),
// n = ct*16 + (l&15),  k = ks*32 + (l>>4)*8 + j,  KS = K/32.
__global__ void k_packw(const float* __restrict__ W, unsigned short* __restrict__ P,
                        int K, int N, int rowoff) {
    int tid = blockIdx.x * 256 + threadIdx.x;
    if (tid >= K * N) return;
    int j = tid & 7;
    int l = (tid >> 3) & 63;
    int rest = tid >> 9;
    int KS = K >> 5;
    int ks = rest % KS;
    int ct = rest / KS;
    int n = ct * 16 + (l & 15);
    int k = ks * 32 + (l >> 4) * 8 + j;
    P[tid] = f2bf(W[(size_t)(rowoff + k) * N + n]);
}

__global__ void k_h2bf(const float* __restrict__ h, unsigned short* __restrict__ hb, int n4) {
    int i = blockIdx.x * 256 + threadIdx.x;
    if (i < n4) {
        float4 v = *(const float4*)(h + (size_t)i * 4);
        ushort4 o;
        o.x = f2bf(v.x); o.y = f2bf(v.y); o.z = f2bf(v.z); o.w = f2bf(v.w);
        *(ushort4*)(hb + (size_t)i * 4) = o;
    }
}

// ---------------- MFMA helpers ----------------
__device__ __forceinline__ void zero_acc(f32x4 (&acc)[4][4]) {
    #pragma unroll
    for (int i = 0; i < 4; ++i)
        #pragma unroll
        for (int c = 0; c < 4; ++c)
            #pragma unroll
            for (int r = 0; r < 4; ++r) acc[i][c][r] = 0.f;
}

template<int KS, int STRIDE>
__device__ __forceinline__ void gemm_step(const unsigned short* A,
                                          const unsigned short* __restrict__ Wp,
                                          int w, int l, f32x4 (&acc)[4][4]) {
    for (int ks = 0; ks < KS; ++ks) {
        bf16x8 a[4], b[4];
        #pragma unroll
        for (int i = 0; i < 4; ++i)
            a[i] = *(const bf16x8*)(A + (i * 16 + (l & 15)) * STRIDE + ks * 32 + (l >> 4) * 8);
        #pragma unroll
        for (int c = 0; c < 4; ++c)
            b[c] = *(const bf16x8*)(Wp + (((4 * w + c) * KS + ks) * 64 + l) * 8);
        #pragma unroll
        for (int i = 0; i < 4; ++i)
            #pragma unroll
            for (int c = 0; c < 4; ++c)
                acc[i][c] = __builtin_amdgcn_mfma_f32_16x16x32_bf16(a[i], b[c], acc[i][c], 0, 0, 0);
    }
}

// ---------------- Q = MLP(h) ----------------
__global__ __launch_bounds__(256) void k_qmlp(
    const unsigned short* __restrict__ hb,
    const unsigned short* __restrict__ W1p, const float* __restrict__ b1,
    const unsigned short* __restrict__ W2p, const float* __restrict__ b2,
    unsigned short* __restrict__ qb)
{
    __shared__ unsigned short sX[64][136];
    __shared__ unsigned short sH[64][264];
    const int t = threadIdx.x, w = t >> 6, l = t & 63;
    const int m0 = blockIdx.x * 64;

    for (int c = t; c < 1024; c += 256) {
        int row = c >> 4, j = c & 15;
        int srcr = m0 + row; if (srcr >= NND) srcr = NND - 1;
        *(bf16x8*)(&sX[row][j * 8]) = *(const bf16x8*)(hb + (size_t)srcr * IND + j * 8);
    }
    __syncthreads();

    f32x4 acc[4][4];
    zero_acc(acc);
    gemm_step<4, 136>(&sX[0][0], W1p, w, l, acc);

    float bias1[4];
    #pragma unroll
    for (int c = 0; c < 4; ++c) bias1[c] = b1[64 * w + 16 * c + (l & 15)];
    #pragma unroll
    for (int i = 0; i < 4; ++i)
        #pragma unroll
        for (int c = 0; c < 4; ++c)
            #pragma unroll
            for (int r = 0; r < 4; ++r) {
                float v = acc[i][c][r] + bias1[c];
                v = v > 0.f ? v : 0.f;
                sH[i * 16 + (l >> 4) * 4 + r][64 * w + 16 * c + (l & 15)] = f2bf(v);
            }
    __syncthreads();

    zero_acc(acc);
    gemm_step<8, 264>(&sH[0][0], W2p, w, l, acc);

    float bias2[4];
    #pragma unroll
    for (int c = 0; c < 4; ++c) bias2[c] = b2[64 * w + 16 * c + (l & 15)];
    #pragma unroll
    for (int i = 0; i < 4; ++i)
        #pragma unroll
        for (int c = 0; c < 4; ++c)
            #pragma unroll
            for (int r = 0; r < 4; ++r) {
                int row = m0 + i * 16 + (l >> 4) * 4 + r;
                if (row < NND)
                    qb[(size_t)row * OD + 64 * w + 16 * c + (l & 15)] =
                        f2bf(acc[i][c][r] + bias2[c]);
            }
}

// ---------------- u = h @ W1part (two at once, no bias/relu) ----------------
__global__ __launch_bounds__(256) void k_lin2(
    const unsigned short* __restrict__ hb,
    const unsigned short* __restrict__ Pd, const unsigned short* __restrict__ Ps,
    unsigned short* __restrict__ outd, unsigned short* __restrict__ outs)
{
    __shared__ unsigned short sX[64][136];
    const int t = threadIdx.x, w = t >> 6, l = t & 63;
    const int m0 = blockIdx.x * 64;

    for (int c = t; c < 1024; c += 256) {
        int row = c >> 4, j = c & 15;
        int srcr = m0 + row; if (srcr >= NND) srcr = NND - 1;
        *(bf16x8*)(&sX[row][j * 8]) = *(const bf16x8*)(hb + (size_t)srcr * IND + j * 8);
    }
    __syncthreads();

    f32x4 acc[4][4];
    zero_acc(acc);
    gemm_step<4, 136>(&sX[0][0], Pd, w, l, acc);
    #pragma unroll
    for (int i = 0; i < 4; ++i)
        #pragma unroll
        for (int c = 0; c < 4; ++c)
            #pragma unroll
            for (int r = 0; r < 4; ++r) {
                int row = m0 + i * 16 + (l >> 4) * 4 + r;
                if (row < NND)
                    outd[(size_t)row * HD + 64 * w + 16 * c + (l & 15)] = f2bf(acc[i][c][r]);
            }

    zero_acc(acc);
    gemm_step<4, 136>(&sX[0][0], Ps, w, l, acc);
    #pragma unroll
    for (int i = 0; i < 4; ++i)
        #pragma unroll
        for (int c = 0; c < 4; ++c)
            #pragma unroll
            for (int r = 0; r < 4; ++r) {
                int row = m0 + i * 16 + (l >> 4) * 4 + r;
                if (row < NND)
                    outs[(size_t)row * HD + 64 * w + 16 * c + (l & 15)] = f2bf(acc[i][c][r]);
            }
}

// ---------------- edge kernels (dst-sorted order) ----------------
struct SmE {
    unsigned short E[64][72];    //  9,216 B  e-tile (K=64 of GEMM1)
    unsigned short H[64][264];   // 33,792 B  hidden / k / alpha*v
    int   Eid[64];
    int   Src[64];
    int   Dst[64];
    float Ex[64][8];
};

// common: stage Eid/Src/Dst + e-tile
__device__ __forceinline__ void stage_edges(SmE& sm, const float* __restrict__ eattr,
                                            const int* __restrict__ eidx,
                                            const int* __restrict__ perm,
                                            int e0, int t) {
    if (t < 64) {
        int eid = perm[e0 + t];
        sm.Eid[t] = eid;
        sm.Src[t] = eidx[eid];
        sm.Dst[t] = eidx[NE + eid];
    }
    __syncthreads();
    for (int c = t; c < 1024; c += 256) {
        int row = c >> 4, j = c & 15;
        float4 v = *(const float4*)(eattr + (size_t)sm.Eid[row] * ED + j * 4);
        ushort4 o; o.x = f2bf(v.x); o.y = f2bf(v.y); o.z = f2bf(v.z); o.w = f2bf(v.w);
        *(ushort4*)(&sm.E[row][j * 4]) = o;
    }
}

// GEMM1(e) + bias -> H', then H = relu(H' + ud[dst] + us[src])
template<typename SM>
__device__ __forceinline__ void hidden_pass(SM& sm,
                                            const unsigned short* __restrict__ W1e,
                                            const float* __restrict__ b1,
                                            const unsigned short* __restrict__ ud,
                                            const unsigned short* __restrict__ us,
                                            int w, int l, int t, f32x4 (&acc)[4][4]) {
    zero_acc(acc);
    gemm_step<2, 72>(&sm.E[0][0], W1e, w, l, acc);
    float bias1[4];
    #pragma unroll
    for (int c = 0; c < 4; ++c) bias1[c] = b1[64 * w + 16 * c + (l & 15)];
    #pragma unroll
    for (int i = 0; i < 4; ++i)
        #pragma unroll
        for (int c = 0; c < 4; ++c)
            #pragma unroll
            for (int r = 0; r < 4; ++r)
                sm.H[i * 16 + (l >> 4) * 4 + r][64 * w + 16 * c + (l & 15)] =
                    f2bf(acc[i][c][r] + bias1[c]);   // pre-relu, pre-u
    __syncthreads();

    // elementwise: thread owns row t>>2, 8 chunks of 8 cols
    {
        int er = t >> 2;
        const unsigned short* udr = ud + (size_t)sm.Dst[er] * HD;
        const unsigned short* usr = us + (size_t)sm.Src[er] * HD;
        bf16x8 vd[8], vs[8];
        #pragma unroll
        for (int j = 0; j < 8; ++j) {
            int col = (j * 4 + (t & 3)) * 8;
            vd[j] = *(const bf16x8*)(udr + col);
            vs[j] = *(const bf16x8*)(usr + col);
        }
        #pragma unroll
        for (int j = 0; j < 8; ++j) {
            int col = (j * 4 + (t & 3)) * 8;
            bf16x8 hv = *(const bf16x8*)(&sm.H[er][col]);
            bf16x8 o;
            #pragma unroll
            for (int u = 0; u < 8; ++u) {
                float x = bf2f((unsigned short)hv[u]) + bf2f((unsigned short)vd[j][u])
                        + bf2f((unsigned short)vs[j][u]);
                o[u] = (short)f2bf(x > 0.f ? x : 0.f);
            }
            *(bf16x8*)(&sm.H[er][col]) = o;
        }
    }
    __syncthreads();
}

// K-pass: ex = exp(q[dst].k/sqrt(32)); exbuf, den
__global__ __launch_bounds__(256, 3) void k_edgeK(
    const float* __restrict__ eattr,
    const int* __restrict__ eidx, const int* __restrict__ perm,
    const unsigned short* __restrict__ W1e, const float* __restrict__ b1,
    const unsigned short* __restrict__ W2,  const float* __restrict__ b2,
    const unsigned short* __restrict__ ud,  const unsigned short* __restrict__ us,
    const unsigned short* __restrict__ qb,
    float* __restrict__ exbuf, float* __restrict__ den)
{
    __shared__ SmE sm;
    const int t = threadIdx.x, w = t >> 6, l = t & 63;
    const int e0 = blockIdx.x * 64;

    stage_edges(sm, eattr, eidx, perm, e0, t);
    __syncthreads();

    f32x4 acc[4][4];
    hidden_pass(sm, W1e, b1, ud, us, w, l, t, acc);

    zero_acc(acc);
    gemm_step<8, 264>(&sm.H[0][0], W2, w, l, acc);

    float bias2[4];
    #pragma unroll
    for (int c = 0; c < 4; ++c) bias2[c] = b2[64 * w + 16 * c + (l & 15)];
    __syncthreads();   // all waves done reading H
    #pragma unroll
    for (int i = 0; i < 4; ++i)
        #pragma unroll
        for (int c = 0; c < 4; ++c)
            #pragma unroll
            for (int r = 0; r < 4; ++r)
                sm.H[i * 16 + (l >> 4) * 4 + r][64 * w + 16 * c + (l & 15)] =
                    f2bf(acc[i][c][r] + bias2[c]);
    __syncthreads();

    const float scale = 0.17677669529663687f;   // 1/sqrt(32)
    for (int p = t; p < 512; p += 256) {
        int er = p >> 3, hh = p & 7;
        int dn = sm.Dst[er];
        const unsigned short* qrow = qb + (size_t)dn * OD + hh * 32;
        float s = 0.f;
        #pragma unroll
        for (int jj = 0; jj < 32; jj += 8) {
            bf16x8 qv = *(const bf16x8*)(qrow + jj);
            bf16x8 kv = *(const bf16x8*)(&sm.H[er][hh * 32 + jj]);
            #pragma unroll
            for (int u = 0; u < 8; ++u)
                s += bf2f((unsigned short)qv[u]) * bf2f((unsigned short)kv[u]);
        }
        float ex = __expf(s * scale);
        exbuf[(size_t)(e0 + er) * NH + hh] = ex;
        sm.Ex[er][hh] = ex;
    }
    __syncthreads();
    if (t < NH) {   // per-head segment-sum of ex into den
        float run = 0.f; int prev = sm.Dst[0];
        for (int er = 0; er < 64; ++er) {
            int dn = sm.Dst[er];
            if (dn != prev) { atomicAdd(&den[prev * NH + t], run); run = 0.f; prev = dn; }
            run += sm.Ex[er][t];
        }
        atomicAdd(&den[prev * NH + t], run);
    }
}

// V-pass: out[dst] += seg-sum( alpha * v )
__global__ __launch_bounds__(256, 3) void k_edgeV(
    const float* __restrict__ eattr,
    const int* __restrict__ eidx, const int* __restrict__ perm,
    const unsigned short* __restrict__ W1e, const float* __restrict__ b1,
    const unsigned short* __restrict__ W2,  const float* __restrict__ b2,
    const unsigned short* __restrict__ ud,  const unsigned short* __restrict__ us,
    const float* __restrict__ exbuf, const float* __restrict__ den,
    float* __restrict__ outp)
{
    __shared__ SmE sm;
    const int t = threadIdx.x, w = t >> 6, l = t & 63;
    const int e0 = blockIdx.x * 64;

    stage_edges(sm, eattr, eidx, perm, e0, t);
    for (int p = t; p < 512; p += 256) {
        int er = p >> 3, hh = p & 7;
        sm.Ex[er][hh] = exbuf[(size_t)(e0 + er) * NH + hh] / den[sm.Dst[er] * NH + hh];
    }
    __syncthreads();

    f32x4 acc[4][4];
    hidden_pass(sm, W1e, b1, ud, us, w, l, t, acc);

    zero_acc(acc);
    gemm_step<8, 264>(&sm.H[0][0], W2, w, l, acc);

    float bias2[4];
    #pragma unroll
    for (int c = 0; c < 4; ++c) bias2[c] = b2[64 * w + 16 * c + (l & 15)];
    __syncthreads();   // all waves done reading H
    #pragma unroll
    for (int i = 0; i < 4; ++i)
        #pragma unroll
        for (int c = 0; c < 4; ++c) {
            int col = 64 * w + 16 * c + (l & 15);
            int hh = col >> 5;
            #pragma unroll
            for (int r = 0; r < 4; ++r) {
                int er = i * 16 + (l >> 4) * 4 + r;
                sm.H[er][col] = f2bf((acc[i][c][r] + bias2[c]) * sm.Ex[er][hh]);
            }
        }
    __syncthreads();
    // column-parallel segment reduction; thread t owns col t
    {
        float run = 0.f; int prev = sm.Dst[0];
        for (int er = 0; er < 64; ++er) {
            int dn = sm.Dst[er];
            if (dn != prev) {
                atomicAdd(outp + (size_t)prev * OD + t, run);
                run = 0.f; prev = dn;
            }
            run += bf2f(sm.H[er][t]);
        }
        atomicAdd(outp + (size_t)prev * OD + t, run);
    }
}

// ---------------- launcher ----------------
extern "C" void kernel_launch(void* const* d_in, const int* in_sizes, int n_in,
                              void* d_out, int out_size, void* d_ws, size_t ws_size,
                              hipStream_t stream)
{
    const float* h   = (const float*)d_in[0];
    const float* e   = (const float*)d_in[1];
    const int*   eid = (const int*)  d_in[2];
    const float* Wk1 = (const float*)d_in[3];
    const float* bk1 = (const float*)d_in[4];
    const float* Wk2 = (const float*)d_in[5];
    const float* bk2 = (const float*)d_in[6];
    const float* Wv1 = (const float*)d_in[7];
    const float* bv1 = (const float*)d_in[8];
    const float* Wv2 = (const float*)d_in[9];
    const float* bv2 = (const float*)d_in[10];
    const float* Wq1 = (const float*)d_in[11];
    const float* bq1 = (const float*)d_in[12];
    const float* Wq2 = (const float*)d_in[13];
    const float* bq2 = (const float*)d_in[14];

    // workspace layout (bytes)
    char* ws = (char*)d_ws;
    unsigned short* hb   = (unsigned short*)(ws + 0);             // 12,800,000
    unsigned short* qb   = (unsigned short*)(ws + 12800000);      // 25,600,000
    unsigned short* udb  = (unsigned short*)(ws + 38400000);      // 25,600,000 (K then V)
    unsigned short* usb  = (unsigned short*)(ws + 64000000);      // 25,600,000 (K then V)
    float*          exb  = (float*)         (ws + 89600000);      // 25,600,000
    float*          den  = (float*)         (ws + 115200000);     //  1,600,000
    int*            cnt  = (int*)           (ws + 116800000);     //    200,000
    int*            head = (int*)           (ws + 117000000);     //    200,000
    int*            perm = (int*)           (ws + 117200000);     //  3,200,000
    unsigned short* Wq1p = (unsigned short*)(ws + 120400000);     //     65,536
    unsigned short* Wq2p = (unsigned short*)(ws + 120465536);     //    131,072
    unsigned short* WeK  = (unsigned short*)(ws + 120596608);     //     32,768
    unsigned short* W2K  = (unsigned short*)(ws + 120629376);     //    131,072
    unsigned short* WdK  = (unsigned short*)(ws + 120760448);     //     65,536
    unsigned short* WsK  = (unsigned short*)(ws + 120825984);     //     65,536
    unsigned short* WeV  = (unsigned short*)(ws + 120891520);     //     32,768
    unsigned short* W2V  = (unsigned short*)(ws + 120924288);     //    131,072
    unsigned short* WdV  = (unsigned short*)(ws + 121055360);     //     65,536
    unsigned short* WsV  = (unsigned short*)(ws + 121120896);     //     65,536
    const size_t needed = 121186432;
    if (ws_size < needed) return;   // insufficient scratch -> fail validation visibly

    hipMemsetAsync(d_out, 0, (size_t)NND * OD * sizeof(float), stream);
    hipMemsetAsync(den, 0, (size_t)NND * NH * sizeof(float), stream);
    hipMemsetAsync(cnt, 0, (size_t)NND * sizeof(int), stream);

    // counting sort of edges by dst
    k_hist<<<(NE + 255) / 256, 256, 0, stream>>>(eid, cnt);
    k_scan<<<1, 1024, 0, stream>>>(cnt, head);
    k_scatter<<<(NE + 255) / 256, 256, 0, stream>>>(eid, head, perm);

    k_h2bf<<<(NND * IND / 4 + 255) / 256, 256, 0, stream>>>(h, hb, NND * IND / 4);

    // weight packs
    k_packw<<<(IND * HD + 255) / 256, 256, 0, stream>>>(Wq1, Wq1p, IND, HD, 0);
    k_packw<<<(HD * OD + 255) / 256, 256, 0, stream>>>(Wq2, Wq2p, HD, OD, 0);
    k_packw<<<(ED * HD + 255) / 256, 256, 0, stream>>>(Wk1, WeK, ED, HD, 0);
    k_packw<<<(HD * OD + 255) / 256, 256, 0, stream>>>(Wk2, W2K, HD, OD, 0);
    k_packw<<<(IND * HD + 255) / 256, 256, 0, stream>>>(Wk1, WdK, IND, HD, 64);
    k_packw<<<(IND * HD + 255) / 256, 256, 0, stream>>>(Wk1, WsK, IND, HD, 192);
    k_packw<<<(ED * HD + 255) / 256, 256, 0, stream>>>(Wv1, WeV, ED, HD, 0);
    k_packw<<<(HD * OD + 255) / 256, 256, 0, stream>>>(Wv2, W2V, HD, OD, 0);
    k_packw<<<(IND * HD + 255) / 256, 256, 0, stream>>>(Wv1, WdV, IND, HD, 64);
    k_packw<<<(IND * HD + 255) / 256, 256, 0, stream>>>(Wv1, WsV, IND, HD, 192);

    k_qmlp<<<(NND + 63) / 64, 256, 0, stream>>>(hb, Wq1p, bq1, Wq2p, bq2, qb);

    // K phase
    k_lin2<<<(NND + 63) / 64, 256, 0, stream>>>(hb, WdK, WsK, udb, usb);
    k_edgeK<<<NE / 64, 256, 0, stream>>>(e, eid, perm, WeK, bk1, W2K, bk2,
                                         udb, usb, qb, exb, den);
    // V phase (reuse u buffers)
    k_lin2<<<(NND + 63) / 64, 256, 0, stream>>>(hb, WdV, WsV, udb, usb);
    k_edgeV<<<NE / 64, 256, 0, stream>>>(e, eid, perm, WeV, bv1, W2V, bv2,
                                         udb, usb, exb, den, (float*)d_out);
}